// Round 2
// baseline (286.774 us; speedup 1.0000x reference)
//
#include <hip/hip_runtime.h>
#include <math.h>

typedef short bf16x8 __attribute__((ext_vector_type(8)));
typedef float f32x4 __attribute__((ext_vector_type(4)));

__device__ __forceinline__ unsigned short f2bf(float x) {
  union { float f; unsigned u; } v; v.f = x;
  unsigned r = v.u + 0x7FFFu + ((v.u >> 16) & 1u);
  return (unsigned short)(r >> 16);
}
__device__ __forceinline__ float bf2f(unsigned short h) {
  union { unsigned u; float f; } v; v.u = ((unsigned)h) << 16; return v.f;
}

// ---------------- workspace layout (bytes) ----------------
#define WS_WHHT 0u          // [768][256] bf16 (W_hh transposed)
#define WS_W1T  393216u     // [512][256] bf16 (W1 transposed)
#define WS_HA   655360u     // [2048][256] f32
#define WS_HB   2752512u    // [2048][256] f32
#define WS_ACTS 4849664u    // [2048][512] bf16
#define WS_LAM  6946816u    // [2048][22] f32
#define WS_KKT  7127040u    // 4 x [11][16] f32
#define WS_SUMS 7129856u    // sumP[11], sumPDOT[11] f32

// ---------------- weight conversion / transpose ----------------
__global__ __launch_bounds__(256) void convert_weights(
    const float* __restrict__ Whh, const float* __restrict__ W1,
    unsigned short* __restrict__ WhhT, unsigned short* __restrict__ W1T)
{
  int idx = blockIdx.x * 256 + threadIdx.x;
  if (idx < 768 * 256) {
    int n = idx >> 8, k = idx & 255;
    WhhT[idx] = f2bf(Whh[k * 768 + n]);
  } else {
    int j = idx - 768 * 256;
    int n = j >> 8, k = j & 255;
    W1T[j] = f2bf(W1[k * 512 + n]);
  }
}

// ---------------- KKT inverses (fp64 Gauss-Jordan in LDS) ----------------
// mat 0: KKT_X (n=15), 1: KKT_Y (n=14), 2: KKT_IX (n=15), 3: KKT_IY (n=14)
__global__ __launch_bounds__(256) void setup_kkt(float* __restrict__ kkt_out,
                                                 float* __restrict__ sums_out)
{
  __shared__ double S[21];
  __shared__ double aug[15][32];
  __shared__ double fbuf[15];
  const int mat = blockIdx.x;
  const int n = (mat == 0 || mat == 2) ? 15 : 14;
  const int twoN = 2 * n;
  if (threadIdx.x == 0) {
    for (int m = 0; m < 21; ++m) S[m] = 0.0;
    for (int s = 0; s < 100; ++s) {
      double t = s * (1.0 / 99.0);
      double p = 1.0;
      for (int m = 0; m < 21; ++m) { S[m] += p; p *= t; }
    }
  }
  __syncthreads();
  for (int idx = threadIdx.x; idx < n * twoN; idx += 256) {
    int r = idx / twoN, c = idx % twoN;
    double v;
    if (c >= n) v = (c - n == r) ? 1.0 : 0.0;
    else if (r < 11 && c < 11) {
      double ptp = S[r + c];
      double pdp = (r >= 1 && c >= 1) ? ((double)(r * c) / 100.0) * S[r + c - 2] : 0.0;
      double pddp = (r >= 2 && c >= 2) ? ((double)(r*(r-1)) * (double)(c*(c-1)) / 10000.0) * S[r + c - 4] : 0.0;
      double dg = (r == c) ? 1.0 : 0.0;
      if (mat == 0)      v = 21.0*dg + 30.0*ptp + pdp + pddp;
      else if (mat == 1) v = 21.0*dg + 32.0*ptp + pdp + pddp;
      else if (mat == 2) v = 20.0*dg + 2.0*pdp;
      else               v = 20.0*dg + 2.0*pdp + ptp;
    } else if (r >= 11 && c >= 11) v = 0.0;
    else {
      int ar = (r >= 11) ? (r - 11) : (c - 11);
      int ac = (r >= 11) ? c : r;
      v = (ar == 0) ? ((ac == 0) ? 1.0 : 0.0)
        : (ar == 1) ? ((ac == 1) ? 0.1 : 0.0)
        : (ar == 2) ? ((ac == 2) ? 0.02 : 0.0)
        : 1.0;
    }
    aug[r][c] = v;
  }
  __syncthreads();
  for (int p = 0; p < n; ++p) {
    double pv = aug[p][p];
    __syncthreads();
    double inv = 1.0 / pv;
    for (int c = threadIdx.x; c < twoN; c += 256) aug[p][c] *= inv;
    __syncthreads();
    if (threadIdx.x < n) fbuf[threadIdx.x] = aug[threadIdx.x][p];
    __syncthreads();
    for (int idx = threadIdx.x; idx < n * twoN; idx += 256) {
      int r = idx / twoN, c = idx % twoN;
      if (r != p) aug[r][c] -= fbuf[r] * aug[p][c];
    }
    __syncthreads();
  }
  for (int idx = threadIdx.x; idx < 11 * n; idx += 256) {
    int r = idx / n, c = idx % n;
    kkt_out[mat * 176 + r * 16 + c] = (float)aug[r][n + c];
  }
  if (mat == 0 && threadIdx.x < 11) {
    int j = threadIdx.x;
    sums_out[j] = (float)S[j];
    sums_out[11 + j] = (j >= 1) ? (float)((double)j / 10.0 * S[j - 1]) : 0.f;
  }
}

// ---------------- GRU step: GEMM(32x(3x64)x256) + fused gate update ----------------
__global__ __launch_bounds__(256) void gru_step(
    const float* __restrict__ Hin, float* __restrict__ Hout,
    const unsigned short* __restrict__ WhhT,
    const float* __restrict__ Wih, const float* __restrict__ gbias,
    const float* __restrict__ h0,
    const float* __restrict__ obs, const float* __restrict__ dimx,
    const float* __restrict__ dimy, const float* __restrict__ psi,
    int step)
{
  __shared__ __align__(16) unsigned short Alds[8192]; // 32 rows x 256 k bf16, chunked
  const int tid = threadIdx.x;
  const int m0 = blockIdx.x * 32;
  const int c0 = blockIdx.y * 64;
  const bool s0 = (step == 0);

  for (int i = 0; i < 4; ++i) {
    int c = tid + 256 * i;
    int kc = c >> 7, rem = c & 127;
    int row = rem >> 2, g = rem & 3;
    int k = kc * 32 + g * 8;
    const float* src = s0 ? (h0 + k) : (Hin + (size_t)(m0 + row) * 256 + k);
    float4 f0 = *(const float4*)(src);
    float4 f1 = *(const float4*)(src + 4);
    union { unsigned short u[8]; int4 v; } pk;
    pk.u[0] = f2bf(f0.x); pk.u[1] = f2bf(f0.y); pk.u[2] = f2bf(f0.z); pk.u[3] = f2bf(f0.w);
    pk.u[4] = f2bf(f1.x); pk.u[5] = f2bf(f1.y); pk.u[6] = f2bf(f1.z); pk.u[7] = f2bf(f1.w);
    *(int4*)(&Alds[c * 8]) = pk.v;
  }
  __syncthreads();

  const int lane = tid & 63, w = tid >> 6;
  const int l15 = lane & 15, g4 = lane >> 4;
  const int ncol = c0 + w * 16 + l15; // h-col in [0,256)

  f32x4 zero4 = {0.f, 0.f, 0.f, 0.f};
  f32x4 acc[2][3];
  for (int a = 0; a < 2; ++a)
    for (int g = 0; g < 3; ++g) acc[a][g] = zero4;

  for (int kc = 0; kc < 8; ++kc) {
    bf16x8 a0 = *(const bf16x8*)(&Alds[(kc * 128 + l15 * 4 + g4) * 8]);
    bf16x8 a1 = *(const bf16x8*)(&Alds[(kc * 128 + (16 + l15) * 4 + g4) * 8]);
    int kk = kc * 32 + g4 * 8;
    #pragma unroll
    for (int gate = 0; gate < 3; ++gate) {
      bf16x8 bfrag = *(const bf16x8*)(&WhhT[(size_t)(gate * 256 + ncol) * 256 + kk]);
      acc[0][gate] = __builtin_amdgcn_mfma_f32_16x16x32_bf16(a0, bfrag, acc[0][gate], 0, 0, 0);
      acc[1][gate] = __builtin_amdgcn_mfma_f32_16x16x32_bf16(a1, bfrag, acc[1][gate], 0, 0, 0);
    }
  }

  float wz[5], wr[5], wn[5];
  #pragma unroll
  for (int f = 0; f < 5; ++f) {
    wz[f] = Wih[f * 768 + ncol];
    wr[f] = Wih[f * 768 + 256 + ncol];
    wn[f] = Wih[f * 768 + 512 + ncol];
  }
  float bz = gbias[ncol], br = gbias[256 + ncol], bn = gbias[512 + ncol];

  #pragma unroll
  for (int mi = 0; mi < 2; ++mi) {
    #pragma unroll
    for (int reg = 0; reg < 4; ++reg) {
      int row = m0 + mi * 16 + g4 * 4 + reg;
      float t0 = obs[row * 20 + step];
      float t1 = obs[row * 20 + 10 + step];
      float t2 = dimx[row * 10 + step];
      float t3 = dimy[row * 10 + step];
      float t4 = psi[row * 10 + step];
      float gz = bz + t0*wz[0] + t1*wz[1] + t2*wz[2] + t3*wz[3] + t4*wz[4];
      float gr = br + t0*wr[0] + t1*wr[1] + t2*wr[2] + t3*wr[3] + t4*wr[4];
      float gn = bn + t0*wn[0] + t1*wn[1] + t2*wn[2] + t3*wn[3] + t4*wn[4];
      float z = 1.f / (1.f + __expf(-(gz + acc[mi][0][reg])));
      float r = 1.f / (1.f + __expf(-(gr + acc[mi][1][reg])));
      float nn = tanhf(gn + r * acc[mi][2][reg]);
      float hold = s0 ? h0[ncol] : Hin[(size_t)row * 256 + ncol];
      Hout[(size_t)row * 256 + ncol] = (1.f - z) * nn + z * hold;
    }
  }
}

// ---------------- MLP layer 1: (2048x512x256) + bias + relu -> bf16 acts ----------------
__global__ __launch_bounds__(256) void mlp1(
    const float* __restrict__ Hin, const unsigned short* __restrict__ W1T,
    const float* __restrict__ b1, unsigned short* __restrict__ acts)
{
  __shared__ __align__(16) unsigned short Alds[8192];
  const int tid = threadIdx.x;
  const int m0 = blockIdx.x * 32;
  const int c0 = blockIdx.y * 128;

  for (int i = 0; i < 4; ++i) {
    int c = tid + 256 * i;
    int kc = c >> 7, rem = c & 127;
    int row = rem >> 2, g = rem & 3;
    int k = kc * 32 + g * 8;
    const float* src = Hin + (size_t)(m0 + row) * 256 + k;
    float4 f0 = *(const float4*)(src);
    float4 f1 = *(const float4*)(src + 4);
    union { unsigned short u[8]; int4 v; } pk;
    pk.u[0] = f2bf(f0.x); pk.u[1] = f2bf(f0.y); pk.u[2] = f2bf(f0.z); pk.u[3] = f2bf(f0.w);
    pk.u[4] = f2bf(f1.x); pk.u[5] = f2bf(f1.y); pk.u[6] = f2bf(f1.z); pk.u[7] = f2bf(f1.w);
    *(int4*)(&Alds[c * 8]) = pk.v;
  }
  __syncthreads();

  const int lane = tid & 63, w = tid >> 6;
  const int l15 = lane & 15, g4 = lane >> 4;
  const int nbase = c0 + w * 32 + l15;

  f32x4 zero4 = {0.f, 0.f, 0.f, 0.f};
  f32x4 acc[2][2];
  for (int a = 0; a < 2; ++a)
    for (int g = 0; g < 2; ++g) acc[a][g] = zero4;

  for (int kc = 0; kc < 8; ++kc) {
    bf16x8 a0 = *(const bf16x8*)(&Alds[(kc * 128 + l15 * 4 + g4) * 8]);
    bf16x8 a1 = *(const bf16x8*)(&Alds[(kc * 128 + (16 + l15) * 4 + g4) * 8]);
    int kk = kc * 32 + g4 * 8;
    #pragma unroll
    for (int cf = 0; cf < 2; ++cf) {
      bf16x8 bfrag = *(const bf16x8*)(&W1T[(size_t)(nbase + cf * 16) * 256 + kk]);
      acc[0][cf] = __builtin_amdgcn_mfma_f32_16x16x32_bf16(a0, bfrag, acc[0][cf], 0, 0, 0);
      acc[1][cf] = __builtin_amdgcn_mfma_f32_16x16x32_bf16(a1, bfrag, acc[1][cf], 0, 0, 0);
    }
  }

  #pragma unroll
  for (int mi = 0; mi < 2; ++mi) {
    #pragma unroll
    for (int cf = 0; cf < 2; ++cf) {
      int col = nbase + cf * 16;
      float bb = b1[col];
      #pragma unroll
      for (int reg = 0; reg < 4; ++reg) {
        int row = m0 + mi * 16 + g4 * 4 + reg;
        float v = acc[mi][cf][reg] + bb;
        acts[(size_t)row * 512 + col] = f2bf(fmaxf(v, 0.f));
      }
    }
  }
}

// ---------------- MLP layer 2: (2048x22x512) -> lam ----------------
__global__ __launch_bounds__(256) void mlp2(
    const unsigned short* __restrict__ acts, const float* __restrict__ W2,
    const float* __restrict__ b2, float* __restrict__ lam)
{
  __shared__ unsigned short Ablk[8 * 520];
  __shared__ float W2s[512 * 22];
  const int tid = threadIdx.x;
  const int m0 = blockIdx.x * 8;
  for (int i = tid; i < 4096; i += 256) {
    int r = i >> 9, k = i & 511;
    Ablk[r * 520 + k] = acts[(size_t)(m0 + r) * 512 + k];
  }
  for (int i = tid; i < 11264; i += 256) W2s[i] = W2[i];
  __syncthreads();
  if (tid < 176) {
    int row = tid / 22, col = tid - (tid / 22) * 22;
    float s = b2[col];
    const unsigned short* ap = &Ablk[row * 520];
    for (int k = 0; k < 512; ++k) s += bf2f(ap[k]) * W2s[k * 22 + col];
    lam[(size_t)(m0 + row) * 22 + col] = s;
  }
}

// ---------------- ADMM solver: one block per batch element ----------------
__global__ __launch_bounds__(128) void solver(
    const float* __restrict__ ise, const float* __restrict__ goal,
    const float* __restrict__ obs, const float* __restrict__ psi,
    const float* __restrict__ dimx, const float* __restrict__ dimy,
    const float* __restrict__ yub, const float* __restrict__ ylb,
    const float* __restrict__ lam, const float* __restrict__ kkt,
    const float* __restrict__ sums, float* __restrict__ out)
{
  __shared__ float Pt[3][11][104];
  __shared__ float red[7][104];
  __shared__ float redout[7][11];
  __shared__ float cx[11], cy[11], lx[11], ly[11], cx0[11], cy0[11];
  __shared__ float cxn[11], cyn[11];
  __shared__ float rhsx[15], rhsy[14];
  __shared__ float xc[30], yc[30], ao[10], bo[10], ao2[10], bo2[10];

  const int b = blockIdx.x;
  const int tid = threadIdx.x;

  if (tid < 100) {
    float t = tid * (1.0f / 99.0f);
    float tjm2 = 0.f, tjm1 = 0.f, tj = 1.f;
    #pragma unroll
    for (int j = 0; j < 11; ++j) {
      Pt[0][j][tid] = tj;
      Pt[1][j][tid] = 0.1f * (float)j * tjm1;
      Pt[2][j][tid] = 0.01f * (float)(j * (j - 1)) * tjm2;
      tjm2 = tjm1; tjm1 = tj; tj *= t;
    }
  }
  if (tid < 10) {
    int o = tid;
    float xo = obs[b * 20 + o], yo = obs[b * 20 + 10 + o];
    float dx = dimx[b * 10 + o], dy = dimy[b * 10 + o], ps = psi[b * 10 + o];
    float sp, cp;
    __sincosf(ps, &sp, &cp);
    float r1 = 0.5f * (dx - dy);
    xc[o * 3] = xo; xc[o * 3 + 1] = xo + r1 * cp; xc[o * 3 + 2] = xo - r1 * cp;
    yc[o * 3] = yo; yc[o * 3 + 1] = yo + r1 * sp; yc[o * 3 + 2] = yo - r1 * sp;
    float rad = 0.5f * dy;
    float av = 3.2f + rad, bv = 1.7f + rad;
    ao[o] = av; bo[o] = bv; ao2[o] = av * av; bo2[o] = bv * bv;
  }
  if (tid < 11) { lx[tid] = lam[b * 22 + tid]; ly[tid] = lam[b * 22 + 11 + tid]; }
  const float vx0 = ise[b * 6 + 2], vy0 = ise[b * 6 + 3];
  if (tid == 0) {
    float x0 = ise[b * 6 + 0], y0 = ise[b * 6 + 1];
    float ax0 = ise[b * 6 + 4], ay0 = ise[b * 6 + 5];
    rhsx[11] = x0; rhsx[12] = vx0; rhsx[13] = ax0; rhsx[14] = goal[b * 2 + 0];
    rhsy[11] = y0; rhsy[12] = vy0; rhsy[13] = ay0;
  }
  {
    float vdes = sqrtf(vx0 * vx0 + vy0 * vy0);
    float gy = goal[b * 2 + 1];
    if (tid < 11) { rhsx[tid] = 2.f * vdes * sums[11 + tid]; rhsy[tid] = gy * sums[tid]; }
  }
  const float yU = yub[b], yL = ylb[b];
  __syncthreads();
  if (tid < 11) {
    const float* K = kkt + 2 * 176 + tid * 16;
    float s = 0.f;
    #pragma unroll
    for (int j = 0; j < 15; ++j) s += K[j] * rhsx[j];
    cx0[tid] = s; cx[tid] = s;
  } else if (tid >= 16 && tid < 27) {
    int i = tid - 16;
    const float* K = kkt + 3 * 176 + i * 16;
    float s = 0.f;
    #pragma unroll
    for (int j = 0; j < 14; ++j) s += K[j] * rhsy[j];
    cy0[i] = s; cy[i] = s;
  }
  __syncthreads();

  float Sbx = 0.f, Sby = 0.f, bvx = 0.f, bvy = 0.f, bax = 0.f, bay = 0.f, lane_t = 0.f;
  for (int it = 0; it < 5; ++it) {
    if (tid < 100) {
      float t = tid * (1.0f / 99.0f);
      float x = 0, y = 0, xd = 0, yd = 0, xdd = 0, ydd = 0;
      {
        float tjm2 = 0, tjm1 = 0, tj = 1;
        #pragma unroll
        for (int j = 0; j < 11; ++j) {
          float cj = cx[j], dj = cy[j];
          x += cj * tj; y += dj * tj;
          float pd = 0.1f * (float)j * tjm1;
          xd += cj * pd; yd += dj * pd;
          float pdd = 0.01f * (float)(j * (j - 1)) * tjm2;
          xdd += cj * pdd; ydd += dj * pdd;
          tjm2 = tjm1; tjm1 = tj; tj *= t;
        }
      }
      Sbx = 0.f; Sby = 0.f;
      for (int oi = 0; oi < 10; ++oi) {
        float A = ao[oi], B = bo[oi], A2 = ao2[oi], B2 = bo2[oi];
        #pragma unroll
        for (int cc = 0; cc < 3; ++cc) {
          int o = oi * 3 + cc;
          float xcc = xc[o], ycc = yc[o];
          float wc = x - xcc, wsv = y - ycc;
          float p = wsv * A, q = wc * B;
          float rin = rsqrtf(p * p + q * q + 1e-20f);
          float ca = q * rin, sa = p * rin;
          float c1 = A2 * ca * ca + B2 * sa * sa;
      float c2 = A * wc * ca + B * wsv * sa;
          float d = fmaxf(1.f, __fdividef(c2, c1));
          Sbx += xcc + A * d * ca;
          Sby += ycc + B * d * sa;
        }
      }
      float av = atan2f(yd, xd);
      float cv, sv;
      if (fabsf(av) > 0.41f) { cv = 0.91712081f; sv = copysignf(0.39860934f, av); }
      else { float ri = rsqrtf(fmaxf(xd * xd + yd * yd, 1e-24f)); cv = xd * ri; sv = yd * ri; }
      float dv = fminf(fmaxf(xd * cv + yd * sv, 0.001f), 18.f);
      bvx = dv * cv; bvy = dv * sv;
      float qa = xdd + 1e-4f, pa = ydd + 1e-4f;
      float ria = rsqrtf(pa * pa + qa * qa + 1e-30f);
      float caa = qa * ria, saa = pa * ria;
      float da = fminf(fmaxf(xdd * caa + ydd * saa, 0.f), 6.f);
      bax = da * caa; bay = da * saa;
      lane_t = fminf(y, yU) - fminf(-y, -yL);
      red[0][tid] = Sbx; red[1][tid] = Sby; red[2][tid] = bvx; red[3][tid] = bvy;
      red[4][tid] = bax; red[5][tid] = bay; red[6][tid] = lane_t;
    }
    __syncthreads();
    if (tid < 77) {
      int a = tid / 11, j = tid - a * 11;
      int wt = (a < 2) ? 0 : (a < 4) ? 1 : (a < 6) ? 2 : 0;
      const float4* rp = (const float4*)(&red[a][0]);
      const float4* wp = (const float4*)(&Pt[wt][j][0]);
      float s = 0.f;
      for (int k = 0; k < 25; ++k) {
        float4 rv = rp[k], wv = wp[k];
        s += rv.x * wv.x + rv.y * wv.y + rv.z * wv.z + rv.w * wv.w;
      }
      redout[a][j] = s;
    }
    __syncthreads();
    if (tid < 11) rhsx[tid] = lx[tid] + cx0[tid] + redout[0][tid] + redout[2][tid] + redout[4][tid];
    else if (tid >= 16 && tid < 27) {
      int j = tid - 16;
      rhsy[j] = ly[j] + cy0[j] + redout[1][j] + redout[3][j] + redout[5][j] + redout[6][j];
    }
    __syncthreads();
    if (tid < 11) {
      const float* K = kkt + tid * 16;
      float s = 0.f;
      #pragma unroll
      for (int j = 0; j < 15; ++j) s += K[j] * rhsx[j];
      cxn[tid] = s;
    } else if (tid >= 16 && tid < 27) {
      int i = tid - 16;
      const float* K = kkt + 176 + i * 16;
      float s = 0.f;
      #pragma unroll
      for (int j = 0; j < 14; ++j) s += K[j] * rhsy[j];
      cyn[i] = s;
    }
    __syncthreads();
    if (tid < 100) {
      float t = tid * (1.0f / 99.0f);
      float xn = 0, yn = 0, xdn = 0, ydn = 0, xddn = 0, yddn = 0;
      {
        float tjm2 = 0, tjm1 = 0, tj = 1;
        #pragma unroll
        for (int j = 0; j < 11; ++j) {
          float cj = cxn[j], dj = cyn[j];
          xn += cj * tj; yn += dj * tj;
          float pd = 0.1f * (float)j * tjm1;
          xdn += cj * pd; ydn += dj * pd;
          float pdd = 0.01f * (float)(j * (j - 1)) * tjm2;
          xddn += cj * pdd; yddn += dj * pdd;
          tjm2 = tjm1; tjm1 = tj; tj *= t;
        }
      }
      red[0][tid] = 30.f * xn - Sbx;
      red[1][tid] = xdn - bvx;
      red[2][tid] = xddn - bax;
      red[3][tid] = 30.f * yn - Sby;
      red[4][tid] = ydn - bvy;
      red[5][tid] = yddn - bay;
      red[6][tid] = 2.f * yn - lane_t;
    }
    __syncthreads();
    if (tid < 77) {
      int a = tid / 11, j = tid - a * 11;
      int wt = (a == 0 || a == 3 || a == 6) ? 0 : (a == 1 || a == 4) ? 1 : 2;
      const float4* rp = (const float4*)(&red[a][0]);
      const float4* wp = (const float4*)(&Pt[wt][j][0]);
      float s = 0.f;
      for (int k = 0; k < 25; ++k) {
        float4 rv = rp[k], wv = wp[k];
        s += rv.x * wv.x + rv.y * wv.y + rv.z * wv.z + rv.w * wv.w;
      }
      redout[a][j] = s;
    }
    __syncthreads();
    if (tid < 11) { lx[tid] -= redout[0][tid] + redout[1][tid] + redout[2][tid]; cx[tid] = cxn[tid]; }
    else if (tid >= 16 && tid < 27) {
      int j = tid - 16;
      ly[j] -= redout[3][j] + redout[4][j] + redout[5][j] + redout[6][j];
      cy[j] = cyn[j];
    }
    __syncthreads();
  }
  if (tid < 11) out[b * 22 + tid] = cx[tid];
  else if (tid >= 16 && tid < 27) out[b * 22 + 11 + (tid - 16)] = cy[tid - 16];
}

extern "C" void kernel_launch(void* const* d_in, const int* in_sizes, int n_in,
                              void* d_out, int out_size, void* d_ws, size_t ws_size,
                              hipStream_t stream) {
  const float* ise  = (const float*)d_in[0];
  const float* goal = (const float*)d_in[1];
  const float* obs  = (const float*)d_in[2];
  const float* psi  = (const float*)d_in[3];
  const float* dimx = (const float*)d_in[4];
  const float* dimy = (const float*)d_in[5];
  const float* yub  = (const float*)d_in[6];
  const float* ylb  = (const float*)d_in[7];
  const float* Wih  = (const float*)d_in[8];
  const float* Whh  = (const float*)d_in[9];
  const float* gb   = (const float*)d_in[10];
  const float* h0   = (const float*)d_in[11];
  const float* W1   = (const float*)d_in[12];
  const float* b1   = (const float*)d_in[13];
  const float* W2   = (const float*)d_in[14];
  const float* b2   = (const float*)d_in[15];

  char* ws = (char*)d_ws;
  unsigned short* WhhT = (unsigned short*)(ws + WS_WHHT);
  unsigned short* W1T  = (unsigned short*)(ws + WS_W1T);
  float* HA   = (float*)(ws + WS_HA);
  float* HB   = (float*)(ws + WS_HB);
  unsigned short* acts = (unsigned short*)(ws + WS_ACTS);
  float* lamb = (float*)(ws + WS_LAM);
  float* kkt  = (float*)(ws + WS_KKT);
  float* sums = (float*)(ws + WS_SUMS);

  convert_weights<<<1280, 256, 0, stream>>>(Whh, W1, WhhT, W1T);
  setup_kkt<<<4, 256, 0, stream>>>(kkt, sums);
  for (int s = 0; s < 10; ++s) {
    const float* hin = (s % 2 == 0) ? HB : HA;
    float* hout = (s % 2 == 0) ? HA : HB;
    gru_step<<<dim3(64, 4), 256, 0, stream>>>(hin, hout, WhhT, Wih, gb, h0,
                                              obs, dimx, dimy, psi, s);
  }
  mlp1<<<dim3(64, 4), 256, 0, stream>>>(HB, W1T, b1, acts);
  mlp2<<<256, 256, 0, stream>>>(acts, W2, b2, lamb);
  solver<<<2048, 128, 0, stream>>>(ise, goal, obs, psi, dimx, dimy, yub, ylb,
                                   lamb, kkt, sums, (float*)d_out);
  (void)in_sizes; (void)n_in; (void)out_size; (void)ws_size;
}

// Round 3
// 265.486 us; speedup vs baseline: 1.0802x; 1.0802x over previous
//
#include <hip/hip_runtime.h>
#include <math.h>

typedef short bf16x8 __attribute__((ext_vector_type(8)));
typedef float f32x4 __attribute__((ext_vector_type(4)));

__device__ __forceinline__ unsigned short f2bf(float x) {
  union { float f; unsigned u; } v; v.f = x;
  unsigned r = v.u + 0x7FFFu + ((v.u >> 16) & 1u);
  return (unsigned short)(r >> 16);
}

// ---------------- workspace layout (bytes) ----------------
#define WS_WAUG 0u          // [768][288] bf16 (Whh^T | Wih^T | bias | 0)
#define WS_W1T  442368u     // [512][256] bf16
#define WS_W2T  704512u     // [32][512] bf16 (cols 22..31 zero)
#define WS_LAM  737280u     // [2048][22] f32
#define WS_KKT  917504u     // 4 x [11][16] f32
#define WS_SUMS 920320u     // sumP[11], sumPDOT[11]

// ---------------- prep: KKT inverses (blocks 0-3) + weight packing ----------------
__global__ __launch_bounds__(256) void prep(
    const float* __restrict__ Whh, const float* __restrict__ Wih,
    const float* __restrict__ gb, const float* __restrict__ W1,
    const float* __restrict__ W2,
    unsigned short* __restrict__ Waug, unsigned short* __restrict__ W1T,
    unsigned short* __restrict__ W2T,
    float* __restrict__ kkt_out, float* __restrict__ sums_out)
{
  __shared__ double S[21];
  __shared__ double aug[15][32];
  __shared__ double fbuf[15];
  if (blockIdx.x < 4) {
    const int mat = blockIdx.x;
    const int n = (mat == 0 || mat == 2) ? 15 : 14;
    const int twoN = 2 * n;
    if (threadIdx.x == 0) {
      for (int m = 0; m < 21; ++m) S[m] = 0.0;
      for (int s = 0; s < 100; ++s) {
        double t = s * (1.0 / 99.0);
        double p = 1.0;
        for (int m = 0; m < 21; ++m) { S[m] += p; p *= t; }
      }
    }
    __syncthreads();
    for (int idx = threadIdx.x; idx < n * twoN; idx += 256) {
      int r = idx / twoN, c = idx % twoN;
      double v;
      if (c >= n) v = (c - n == r) ? 1.0 : 0.0;
      else if (r < 11 && c < 11) {
        double ptp = S[r + c];
        double pdp = (r >= 1 && c >= 1) ? ((double)(r * c) / 100.0) * S[r + c - 2] : 0.0;
        double pddp = (r >= 2 && c >= 2) ? ((double)(r*(r-1)) * (double)(c*(c-1)) / 10000.0) * S[r + c - 4] : 0.0;
        double dg = (r == c) ? 1.0 : 0.0;
        if (mat == 0)      v = 21.0*dg + 30.0*ptp + pdp + pddp;
        else if (mat == 1) v = 21.0*dg + 32.0*ptp + pdp + pddp;
        else if (mat == 2) v = 20.0*dg + 2.0*pdp;
        else               v = 20.0*dg + 2.0*pdp + ptp;
      } else if (r >= 11 && c >= 11) v = 0.0;
      else {
        int ar = (r >= 11) ? (r - 11) : (c - 11);
        int ac = (r >= 11) ? c : r;
        v = (ar == 0) ? ((ac == 0) ? 1.0 : 0.0)
          : (ar == 1) ? ((ac == 1) ? 0.1 : 0.0)
          : (ar == 2) ? ((ac == 2) ? 0.02 : 0.0)
          : 1.0;
      }
      aug[r][c] = v;
    }
    __syncthreads();
    for (int p = 0; p < n; ++p) {
      double pv = aug[p][p];
      __syncthreads();
      double inv = 1.0 / pv;
      for (int c = threadIdx.x; c < twoN; c += 256) aug[p][c] *= inv;
      __syncthreads();
      if (threadIdx.x < n) fbuf[threadIdx.x] = aug[threadIdx.x][p];
      __syncthreads();
      for (int idx = threadIdx.x; idx < n * twoN; idx += 256) {
        int r = idx / twoN, c = idx % twoN;
        if (r != p) aug[r][c] -= fbuf[r] * aug[p][c];
      }
      __syncthreads();
    }
    for (int idx = threadIdx.x; idx < 11 * n; idx += 256) {
      int r = idx / n, c = idx % n;
      kkt_out[mat * 176 + r * 16 + c] = (float)aug[r][n + c];
    }
    if (mat == 0 && threadIdx.x < 11) {
      int j = threadIdx.x;
      sums_out[j] = (float)S[j];
      sums_out[11 + j] = (j >= 1) ? (float)((double)j / 10.0 * S[j - 1]) : 0.f;
    }
    return;
  }
  int idx = (blockIdx.x - 4) * 256 + threadIdx.x;
  if (idx < 221184) {           // Waug[col][k], k in [0,288)
    int col = idx / 288, k = idx - col * 288;
    float v;
    if (k < 256)       v = Whh[k * 768 + col];
    else if (k < 261)  v = Wih[(k - 256) * 768 + col];
    else if (k == 261) v = gb[col];
    else               v = 0.f;
    Waug[idx] = f2bf(v);
  } else if (idx < 221184 + 131072) {
    int j = idx - 221184;
    int col = j >> 8, k = j & 255;
    W1T[j] = f2bf(W1[k * 512 + col]);
  } else if (idx < 221184 + 131072 + 16384) {
    int j = idx - 352256;
    int col = j >> 9, k = j & 511;
    W2T[j] = f2bf(col < 22 ? W2[k * 22 + col] : 0.f);
  }
}

// ---------------- persistent GRU(10 steps) + MLP1 + MLP2: 64 blocks x 512 ----------------
#define MFMA __builtin_amdgcn_mfma_f32_16x16x32_bf16
__global__ __launch_bounds__(512, 1) void gru_mlp(
    const float* __restrict__ h0, const unsigned short* __restrict__ Waug,
    const float* __restrict__ obs, const float* __restrict__ dimx,
    const float* __restrict__ dimy, const float* __restrict__ psi,
    const unsigned short* __restrict__ W1T, const float* __restrict__ b1,
    const unsigned short* __restrict__ W2T, const float* __restrict__ b2,
    float* __restrict__ lam)
{
  __shared__ __align__(16) unsigned short A[9216];     // [kc9][row32][g4][e8]
  __shared__ __align__(16) unsigned short acts[16384]; // [kc16][row32][g4][e8]
  __shared__ float fl[32][52];                         // [row][f*10+s]
  const int tid = threadIdx.x;
  const int m0 = blockIdx.x * 32;
  const int lane = tid & 63, w = tid >> 6;
  const int l15 = lane & 15, g4 = lane >> 4;

  for (int i = tid; i < 1600; i += 512) {
    int row = i / 50, r = i - row * 50;
    int f = r / 10, s = r - f * 10;
    int gr = m0 + row;
    float v = (f == 0) ? obs[gr * 20 + s] : (f == 1) ? obs[gr * 20 + 10 + s]
            : (f == 2) ? dimx[gr * 10 + s] : (f == 3) ? dimy[gr * 10 + s]
            : psi[gr * 10 + s];
    fl[row][f * 10 + s] = v;
  }
  for (int i = tid; i < 8192; i += 512) {
    int col = ((i >> 10) << 5) + (i & 31);
    A[i] = f2bf(h0[col]);
  }
  for (int i = tid; i < 1024; i += 512) A[8192 + i] = 0;
  if (tid < 192) {
    int row = tid / 6, e = tid - row * 6;
    float v = (e < 5) ? fl[row][e * 10 + 0] : 1.0f;
    A[(8 * 32 + row) * 32 + e] = f2bf(v);
  }
  float hreg[2][2][4];
  #pragma unroll
  for (int nt = 0; nt < 2; ++nt) {
    float hv = h0[w * 32 + nt * 16 + l15];
    #pragma unroll
    for (int mi = 0; mi < 2; ++mi)
      #pragma unroll
      for (int rg = 0; rg < 4; ++rg) hreg[mi][nt][rg] = hv;
  }
  __syncthreads();

  for (int s = 0; s < 10; ++s) {
    f32x4 az[2][2], ar_[2][2], anh[2][2], anx[2][2];
    #pragma unroll
    for (int mi = 0; mi < 2; ++mi)
      #pragma unroll
      for (int nt = 0; nt < 2; ++nt) {
        az[mi][nt] = (f32x4){0.f,0.f,0.f,0.f}; ar_[mi][nt] = (f32x4){0.f,0.f,0.f,0.f};
        anh[mi][nt] = (f32x4){0.f,0.f,0.f,0.f}; anx[mi][nt] = (f32x4){0.f,0.f,0.f,0.f};
      }
    #pragma unroll
    for (int kc = 0; kc < 9; ++kc) {
      bf16x8 a0 = *(const bf16x8*)&A[((kc * 32 + l15) * 4 + g4) * 8];
      bf16x8 a1 = *(const bf16x8*)&A[((kc * 32 + 16 + l15) * 4 + g4) * 8];
      int kk = kc * 32 + g4 * 8;
      #pragma unroll
      for (int nt = 0; nt < 2; ++nt) {
        int col = w * 32 + nt * 16 + l15;
        bf16x8 bz = *(const bf16x8*)&Waug[(size_t)col * 288 + kk];
        bf16x8 br = *(const bf16x8*)&Waug[(size_t)(256 + col) * 288 + kk];
        bf16x8 bn = *(const bf16x8*)&Waug[(size_t)(512 + col) * 288 + kk];
        az[0][nt] = MFMA(a0, bz, az[0][nt], 0, 0, 0);
        az[1][nt] = MFMA(a1, bz, az[1][nt], 0, 0, 0);
        ar_[0][nt] = MFMA(a0, br, ar_[0][nt], 0, 0, 0);
        ar_[1][nt] = MFMA(a1, br, ar_[1][nt], 0, 0, 0);
        if (kc < 8) {
          anh[0][nt] = MFMA(a0, bn, anh[0][nt], 0, 0, 0);
          anh[1][nt] = MFMA(a1, bn, anh[1][nt], 0, 0, 0);
        } else {
          anx[0][nt] = MFMA(a0, bn, anx[0][nt], 0, 0, 0);
          anx[1][nt] = MFMA(a1, bn, anx[1][nt], 0, 0, 0);
        }
      }
    }
    __syncthreads();   // all A reads complete before rewrite
    #pragma unroll
    for (int mi = 0; mi < 2; ++mi)
      #pragma unroll
      for (int nt = 0; nt < 2; ++nt) {
        int col = w * 32 + nt * 16 + l15;
        #pragma unroll
        for (int rg = 0; rg < 4; ++rg) {
          int row = mi * 16 + g4 * 4 + rg;
          float z = __builtin_amdgcn_rcpf(1.f + __expf(-az[mi][nt][rg]));
          float r = __builtin_amdgcn_rcpf(1.f + __expf(-ar_[mi][nt][rg]));
          float narg = anx[mi][nt][rg] + r * anh[mi][nt][rg];
          float nn = 1.f - 2.f * __builtin_amdgcn_rcpf(__expf(2.f * narg) + 1.f);
          float hnew = (1.f - z) * nn + z * hreg[mi][nt][rg];
          hreg[mi][nt][rg] = hnew;
          A[((w * 32 + row) * 4 + ((col >> 3) & 3)) * 8 + (col & 7)] = f2bf(hnew);
        }
      }
    if (s < 9 && tid < 192) {
      int row = tid / 6, e = tid - row * 6;
      float v = (e < 5) ? fl[row][e * 10 + s + 1] : 1.0f;
      A[(8 * 32 + row) * 32 + e] = f2bf(v);
    }
    __syncthreads();
  }

  // ---- MLP1 ----
  {
    f32x4 acc1[2][4];
    #pragma unroll
    for (int mi = 0; mi < 2; ++mi)
      #pragma unroll
      for (int nt = 0; nt < 4; ++nt) acc1[mi][nt] = (f32x4){0.f,0.f,0.f,0.f};
    #pragma unroll
    for (int kc = 0; kc < 8; ++kc) {
      bf16x8 a0 = *(const bf16x8*)&A[((kc * 32 + l15) * 4 + g4) * 8];
      bf16x8 a1 = *(const bf16x8*)&A[((kc * 32 + 16 + l15) * 4 + g4) * 8];
      int kk = kc * 32 + g4 * 8;
      #pragma unroll
      for (int nt = 0; nt < 4; ++nt) {
        int col = w * 64 + nt * 16 + l15;
        bf16x8 b = *(const bf16x8*)&W1T[(size_t)col * 256 + kk];
        acc1[0][nt] = MFMA(a0, b, acc1[0][nt], 0, 0, 0);
        acc1[1][nt] = MFMA(a1, b, acc1[1][nt], 0, 0, 0);
      }
    }
    #pragma unroll
    for (int mi = 0; mi < 2; ++mi)
      #pragma unroll
      for (int nt = 0; nt < 4; ++nt) {
        int col = w * 64 + nt * 16 + l15;
        float bb = b1[col];
        #pragma unroll
        for (int rg = 0; rg < 4; ++rg) {
          int row = mi * 16 + g4 * 4 + rg;
          float v = fmaxf(acc1[mi][nt][rg] + bb, 0.f);
          acts[(((col >> 5) * 32 + row) * 4 + ((col >> 3) & 3)) * 8 + (col & 7)] = f2bf(v);
        }
      }
  }
  __syncthreads();

  // ---- MLP2 (waves 0-3) ----
  if (w < 4) {
    int mi = w >> 1, nt = w & 1;
    int col = nt * 16 + l15;
    f32x4 a2 = {0.f, 0.f, 0.f, 0.f};
    #pragma unroll
    for (int kc = 0; kc < 16; ++kc) {
      bf16x8 a = *(const bf16x8*)&acts[((kc * 32 + mi * 16 + l15) * 4 + g4) * 8];
      bf16x8 b = *(const bf16x8*)&W2T[(size_t)col * 512 + kc * 32 + g4 * 8];
      a2 = MFMA(a, b, a2, 0, 0, 0);
    }
    if (col < 22) {
      float bb = b2[col];
      #pragma unroll
      for (int rg = 0; rg < 4; ++rg) {
        int row = m0 + mi * 16 + g4 * 4 + rg;
        lam[row * 22 + col] = a2[rg] + bb;
      }
    }
  }
}

// ---------------- ADMM solver ----------------
__global__ __launch_bounds__(128) void solver(
    const float* __restrict__ ise, const float* __restrict__ goal,
    const float* __restrict__ obs, const float* __restrict__ psi,
    const float* __restrict__ dimx, const float* __restrict__ dimy,
    const float* __restrict__ yub, const float* __restrict__ ylb,
    const float* __restrict__ lam, const float* __restrict__ kkt,
    const float* __restrict__ sums, float* __restrict__ out)
{
  __shared__ __align__(16) float Pt[3][11][108];
  __shared__ __align__(16) float red[7][108];
  __shared__ float redout[7][11];
  __shared__ float cx[11], cy[11], lx[11], ly[11], cx0[11], cy0[11];
  __shared__ float cxn[11], cyn[11];
  __shared__ float rhsx[15], rhsy[14];
  __shared__ float xc[30], yc[30], sa_[10], sb_[10], sab[10], sab2[10];

  const int b = blockIdx.x;
  const int tid = threadIdx.x;

  if (tid < 100) {
    float t = tid * (1.0f / 99.0f);
    float tjm2 = 0.f, tjm1 = 0.f, tj = 1.f;
    #pragma unroll
    for (int j = 0; j < 11; ++j) {
      Pt[0][j][tid] = tj;
      Pt[1][j][tid] = 0.1f * (float)j * tjm1;
      Pt[2][j][tid] = 0.01f * (float)(j * (j - 1)) * tjm2;
      tjm2 = tjm1; tjm1 = tj; tj *= t;
    }
  }
  if (tid < 10) {
    int o = tid;
    float xo = obs[b * 20 + o], yo = obs[b * 20 + 10 + o];
    float dx = dimx[b * 10 + o], dy = dimy[b * 10 + o], ps = psi[b * 10 + o];
    float sp, cp;
    __sincosf(ps, &sp, &cp);
    float r1 = 0.5f * (dx - dy);
    xc[o * 3] = xo; xc[o * 3 + 1] = xo + r1 * cp; xc[o * 3 + 2] = xo - r1 * cp;
    yc[o * 3] = yo; yc[o * 3 + 1] = yo + r1 * sp; yc[o * 3 + 2] = yo - r1 * sp;
    float rad = 0.5f * dy;
    float av = 3.2f + rad, bv = 1.7f + rad;
    sa_[o] = av; sb_[o] = bv; sab[o] = av * bv; sab2[o] = av * bv * av * bv;
  }
  if (tid < 11) { lx[tid] = lam[b * 22 + tid]; ly[tid] = lam[b * 22 + 11 + tid]; }
  const float vx0 = ise[b * 6 + 2], vy0 = ise[b * 6 + 3];
  if (tid == 0) {
    float x0 = ise[b * 6 + 0], y0 = ise[b * 6 + 1];
    float ax0 = ise[b * 6 + 4], ay0 = ise[b * 6 + 5];
    rhsx[11] = x0; rhsx[12] = vx0; rhsx[13] = ax0; rhsx[14] = goal[b * 2 + 0];
    rhsy[11] = y0; rhsy[12] = vy0; rhsy[13] = ay0;
  }
  {
    float vdes = sqrtf(vx0 * vx0 + vy0 * vy0);
    float gy = goal[b * 2 + 1];
    if (tid < 11) { rhsx[tid] = 2.f * vdes * sums[11 + tid]; rhsy[tid] = gy * sums[tid]; }
  }
  const float yU = yub[b], yL = ylb[b];
  __syncthreads();
  if (tid < 11) {
    const float* K = kkt + 2 * 176 + tid * 16;
    float s = 0.f;
    #pragma unroll
    for (int j = 0; j < 15; ++j) s += K[j] * rhsx[j];
    cx0[tid] = s; cx[tid] = s;
  } else if (tid >= 16 && tid < 27) {
    int i = tid - 16;
    const float* K = kkt + 3 * 176 + i * 16;
    float s = 0.f;
    #pragma unroll
    for (int j = 0; j < 14; ++j) s += K[j] * rhsy[j];
    cy0[i] = s; cy[i] = s;
  }
  __syncthreads();

  float Sbx = 0.f, Sby = 0.f, bvx = 0.f, bvy = 0.f, bax = 0.f, bay = 0.f, lane_t = 0.f;
  for (int it = 0; it < 5; ++it) {
    if (tid < 100) {
      float t = tid * (1.0f / 99.0f);
      float x = 0, y = 0, xd = 0, yd = 0, xdd = 0, ydd = 0;
      {
        float tjm2 = 0, tjm1 = 0, tj = 1;
        #pragma unroll
        for (int j = 0; j < 11; ++j) {
          float cj = cx[j], dj = cy[j];
          x += cj * tj; y += dj * tj;
          float pd = 0.1f * (float)j * tjm1;
          xd += cj * pd; yd += dj * pd;
          float pdd = 0.01f * (float)(j * (j - 1)) * tjm2;
          xdd += cj * pdd; ydd += dj * pdd;
          tjm2 = tjm1; tjm1 = tj; tj *= t;
        }
      }
      // collapsed ellipse projection: outside -> (x,y); inside -> xcc + wc*(ab/h)
      Sbx = 0.f; Sby = 0.f;
      for (int oi = 0; oi < 10; ++oi) {
        float A = sa_[oi], B = sb_[oi], AB = sab[oi], AB2 = sab2[oi];
        #pragma unroll
        for (int cc = 0; cc < 3; ++cc) {
          int o = oi * 3 + cc;
          float xcc = xc[o], ycc = yc[o];
          float wc = x - xcc, wsv = y - ycc;
          float p = wsv * A, q = wc * B;
          float h2 = p * p + q * q;
          float rin = rsqrtf(h2 + 1e-20f);
          float sc = AB * rin;
          bool outside = h2 >= AB2;
          Sbx += outside ? x : fmaf(wc, sc, xcc);
          Sby += outside ? y : fmaf(wsv, sc, ycc);
        }
      }
      // velocity projection, no atan2: clip iff xd<=0 or |yd| > xd*tan(0.41)
      bool clipv = (xd <= 0.f) || (fabsf(yd) > xd * 0.43463135f);
      float cv, sv;
      if (clipv) { cv = 0.91712081f; sv = copysignf(0.39860934f, yd); }
      else { float ri = rsqrtf(fmaxf(xd * xd + yd * yd, 1e-24f)); cv = xd * ri; sv = yd * ri; }
      float dv = fminf(fmaxf(xd * cv + yd * sv, 0.001f), 18.f);
      bvx = dv * cv; bvy = dv * sv;
      float qa = xdd + 1e-4f, pa = ydd + 1e-4f;
      float ria = rsqrtf(pa * pa + qa * qa + 1e-30f);
      float caa = qa * ria, saa = pa * ria;
      float da = fminf(fmaxf(xdd * caa + ydd * saa, 0.f), 6.f);
      bax = da * caa; bay = da * saa;
      lane_t = fminf(y, yU) - fminf(-y, -yL);
      red[0][tid] = Sbx; red[1][tid] = Sby; red[2][tid] = bvx; red[3][tid] = bvy;
      red[4][tid] = bax; red[5][tid] = bay; red[6][tid] = lane_t;
    }
    __syncthreads();
    if (tid < 77) {
      int a = tid / 11, j = tid - a * 11;
      int wt = (a < 2) ? 0 : (a < 4) ? 1 : (a < 6) ? 2 : 0;
      const float4* rp = (const float4*)(&red[a][0]);
      const float4* wp = (const float4*)(&Pt[wt][j][0]);
      float s = 0.f;
      for (int k = 0; k < 25; ++k) {
        float4 rv = rp[k], wv = wp[k];
        s += rv.x * wv.x + rv.y * wv.y + rv.z * wv.z + rv.w * wv.w;
      }
      redout[a][j] = s;
    }
    __syncthreads();
    if (tid < 11) rhsx[tid] = lx[tid] + cx0[tid] + redout[0][tid] + redout[2][tid] + redout[4][tid];
    else if (tid >= 16 && tid < 27) {
      int j = tid - 16;
      rhsy[j] = ly[j] + cy0[j] + redout[1][j] + redout[3][j] + redout[5][j] + redout[6][j];
    }
    __syncthreads();
    if (tid < 11) {
      const float* K = kkt + tid * 16;
      float s = 0.f;
      #pragma unroll
      for (int j = 0; j < 15; ++j) s += K[j] * rhsx[j];
      cxn[tid] = s;
    } else if (tid >= 16 && tid < 27) {
      int i = tid - 16;
      const float* K = kkt + 176 + i * 16;
      float s = 0.f;
      #pragma unroll
      for (int j = 0; j < 14; ++j) s += K[j] * rhsy[j];
      cyn[i] = s;
    }
    __syncthreads();
    if (tid < 100) {
      float t = tid * (1.0f / 99.0f);
      float xn = 0, yn = 0, xdn = 0, ydn = 0, xddn = 0, yddn = 0;
      {
        float tjm2 = 0, tjm1 = 0, tj = 1;
        #pragma unroll
        for (int j = 0; j < 11; ++j) {
          float cj = cxn[j], dj = cyn[j];
          xn += cj * tj; yn += dj * tj;
          float pd = 0.1f * (float)j * tjm1;
          xdn += cj * pd; ydn += dj * pd;
          float pdd = 0.01f * (float)(j * (j - 1)) * tjm2;
          xddn += cj * pdd; yddn += dj * pdd;
          tjm2 = tjm1; tjm1 = tj; tj *= t;
        }
      }
      red[0][tid] = 30.f * xn - Sbx;
      red[1][tid] = xdn - bvx;
      red[2][tid] = xddn - bax;
      red[3][tid] = 30.f * yn - Sby;
      red[4][tid] = ydn - bvy;
      red[5][tid] = yddn - bay;
      red[6][tid] = 2.f * yn - lane_t;
    }
    __syncthreads();
    if (tid < 77) {
      int a = tid / 11, j = tid - a * 11;
      int wt = (a == 0 || a == 3 || a == 6) ? 0 : (a == 1 || a == 4) ? 1 : 2;
      const float4* rp = (const float4*)(&red[a][0]);
      const float4* wp = (const float4*)(&Pt[wt][j][0]);
      float s = 0.f;
      for (int k = 0; k < 25; ++k) {
        float4 rv = rp[k], wv = wp[k];
        s += rv.x * wv.x + rv.y * wv.y + rv.z * wv.z + rv.w * wv.w;
      }
      redout[a][j] = s;
    }
    __syncthreads();
    if (tid < 11) { lx[tid] -= redout[0][tid] + redout[1][tid] + redout[2][tid]; cx[tid] = cxn[tid]; }
    else if (tid >= 16 && tid < 27) {
      int j = tid - 16;
      ly[j] -= redout[3][j] + redout[4][j] + redout[5][j] + redout[6][j];
      cy[j] = cyn[j];
    }
    __syncthreads();
  }
  if (tid < 11) out[b * 22 + tid] = cx[tid];
  else if (tid >= 16 && tid < 27) out[b * 22 + 11 + (tid - 16)] = cy[tid - 16];
}

extern "C" void kernel_launch(void* const* d_in, const int* in_sizes, int n_in,
                              void* d_out, int out_size, void* d_ws, size_t ws_size,
                              hipStream_t stream) {
  const float* ise  = (const float*)d_in[0];
  const float* goal = (const float*)d_in[1];
  const float* obs  = (const float*)d_in[2];
  const float* psi  = (const float*)d_in[3];
  const float* dimx = (const float*)d_in[4];
  const float* dimy = (const float*)d_in[5];
  const float* yub  = (const float*)d_in[6];
  const float* ylb  = (const float*)d_in[7];
  const float* Wih  = (const float*)d_in[8];
  const float* Whh  = (const float*)d_in[9];
  const float* gb   = (const float*)d_in[10];
  const float* h0   = (const float*)d_in[11];
  const float* W1   = (const float*)d_in[12];
  const float* b1   = (const float*)d_in[13];
  const float* W2   = (const float*)d_in[14];
  const float* b2   = (const float*)d_in[15];

  char* ws = (char*)d_ws;
  unsigned short* Waug = (unsigned short*)(ws + WS_WAUG);
  unsigned short* W1T  = (unsigned short*)(ws + WS_W1T);
  unsigned short* W2T  = (unsigned short*)(ws + WS_W2T);
  float* lamb = (float*)(ws + WS_LAM);
  float* kkt  = (float*)(ws + WS_KKT);
  float* sums = (float*)(ws + WS_SUMS);

  prep<<<1444, 256, 0, stream>>>(Whh, Wih, gb, W1, W2, Waug, W1T, W2T, kkt, sums);
  gru_mlp<<<64, 512, 0, stream>>>(h0, Waug, obs, dimx, dimy, psi, W1T, b1, W2T, b2, lamb);
  solver<<<2048, 128, 0, stream>>>(ise, goal, obs, psi, dimx, dimy, yub, ylb,
                                   lamb, kkt, sums, (float*)d_out);
  (void)in_sizes; (void)n_in; (void)out_size; (void)ws_size;
}